// Round 18
// baseline (173.633 us; speedup 1.0000x reference)
//
#include <hip/hip_runtime.h>
#include <hip/hip_bf16.h>
#include <math.h>

// Problem constants
#define TT 2048
#define BB 2
#define EE 1024
#define HH 16
#define DD 64
#define RR (TT*BB)   // 4096 rows (t*B+b)

typedef __bf16 bf16x8 __attribute__((ext_vector_type(8)));
typedef float  floatx4 __attribute__((ext_vector_type(4)));

// RNE float->bf16 bit conversion
__device__ __forceinline__ unsigned short f2b(float f) {
    union { float f; unsigned u; } x{f};
    return (unsigned short)((x.u + 0x7FFFu + ((x.u >> 16) & 1u)) >> 16);
}
__device__ __forceinline__ float b2f_lo(unsigned u) {
    union { unsigned u; float f; } x{u << 16}; return x.f;
}
__device__ __forceinline__ float b2f_hi(unsigned u) {
    union { unsigned u; float f; } x{u & 0xffff0000u}; return x.f;
}

// native v_exp_f32: computes 2^x
__device__ __forceinline__ float exp2_fast(float x) {
    return __builtin_amdgcn_exp2f(x);
}

typedef const __attribute__((address_space(1))) unsigned int as1_u32;
typedef __attribute__((address_space(3))) unsigned int as3_u32;
__device__ __forceinline__ void gload16(const void* g, void* l) {
    // async global->LDS, 16B per lane; LDS dest = wave-uniform base + lane*16
    __builtin_amdgcn_global_load_lds((as1_u32*)g, (as3_u32*)l, 16, 0, 0);
}

// Q projection scale: D^-0.5 * log2(e)  (so attention uses exp2 directly)
#define SCALE_Q 0.18033688011112042f

// LDS chunk swizzle over 8 chunks/row (measured 0 conflicts in round-8 attn
// for both the permuted-row and 16-consecutive-row b128 read patterns).
__device__ __forceinline__ int swz(int r) {
    return (r & 7) ^ (((r >> 3) & 3) << 1);
}

// ---------------------------------------------------------------------------
// pack: fp32 -> bf16. base (ushort): [0,4M) X | [4M,7M) Wq|Wk|Wv ; Wo -> wob.
// ---------------------------------------------------------------------------
__global__ __launch_bounds__(256)
void pack_bf16(const float* __restrict__ x,  const float* __restrict__ wq,
               const float* __restrict__ wk, const float* __restrict__ wv,
               const float* __restrict__ wo, unsigned short* __restrict__ base,
               unsigned short* __restrict__ wob)
{
    const size_t M4 = (size_t)4 << 20, M7 = (size_t)7 << 20;
    const size_t e0 = ((size_t)blockIdx.x * 256 + threadIdx.x) * 8;
    const float* src;
    unsigned short* dst;
    if (e0 < M4) {
        src = x + e0; dst = base + e0;
    } else if (e0 < M7) {
        const int seg = (int)((e0 >> 20) - 4);
        const float* wsrc[3] = {wq, wk, wv};
        src = wsrc[seg] + (e0 & ((1u << 20) - 1));
        dst = base + e0;
    } else {
        src = wo + (e0 - M7); dst = wob + (e0 - M7);
    }
    const float4 a = *(const float4*)src;
    const float4 b = *(const float4*)(src + 4);
    union { unsigned short u[8]; uint4 v; } p;
    p.u[0] = f2b(a.x); p.u[1] = f2b(a.y); p.u[2] = f2b(a.z); p.u[3] = f2b(a.w);
    p.u[4] = f2b(b.x); p.u[5] = f2b(b.y); p.u[6] = f2b(b.z); p.u[7] = f2b(b.w);
    *(uint4*)dst = p.v;
}

// ---------------------------------------------------------------------------
// bf16 MFMA GEMM, BK=64, 2-buffer pipeline with RAW barrier + counted wait.
// R17: MODE0 BM 128 -> 64 to kill the residency tail: grid (64,24) = 1536
// blocks, LDS 48KB -> 3 blocks/CU -> EXACTLY 2.0 residency rounds (was 768
// blocks @ 2/CU = 1.5 rounds: last 256 blocks ran with half the CU idle).
// BN=128 kept so QKV-boundary (which = j0>>10) and V-transpose geometry
// stay proven. gemm1 empirics (NT=2 thin shape) bound the thin-penalty ~10%.
// T1 XCD swizzle, MODE-dependent grid width:
//   MODE0: L = by*64+bx; g=L&7, s=L>>3 (<192); bx'=g*8+(s&7), by'=s>>3.
//   MODE1: L = by*32+bx; g=L&7, s=L>>3 (<64);  bx'=g*4+(s&3), by'=s>>2.
// MODE 0 (QKV): 64x128 tile, grid (64,24)=1536. LDS 48KB (3 blk/CU).
// MODE 1 (out): 128x64 tile, grid (32,16)=512. LDS 48KB (2/CU exactly).
// ---------------------------------------------------------------------------
template<int MODE>
__global__ __launch_bounds__(256)
void gemm_mfma(const unsigned short* __restrict__ A,
               const unsigned short* __restrict__ Bw,
               const float* __restrict__ b0, const float* __restrict__ b1,
               const float* __restrict__ b2,
               void* __restrict__ out0, void* __restrict__ out1,
               void* __restrict__ out2)
{
    constexpr int BM = (MODE == 0) ? 64 : 128;
    constexpr int BN = (MODE == 0) ? 128 : 64;
    constexpr int MT = BM / 32;           // wave rows: BM/2 (16 per mt)
    constexpr int NT = (MODE == 0) ? 4 : 2;  // wave cols: 64 / 32
    constexpr int RA = BM / 32;           // staging rounds (256 slots each)
    constexpr int RB = BN / 32;
    constexpr int ABYTES = BM * 128;          // A K-tile bytes (BM x 64 bf16)
    constexpr int BUFB   = (BM + BN) * 128;   // one K-tile buffer (A then B)
    __shared__ __align__(16) unsigned char smem[2 * BUFB];

    const int tid  = threadIdx.x;
    const int w    = tid >> 6;
    const int lane = tid & 63;
    const int quad = lane >> 4;
    const int l15  = lane & 15;
    const int wm   = w & 1;
    const int wn   = w >> 1;

    // T1 XCD swizzle: linear dispatch id -> (XCD-stripe i0, j0)
    int bx, by;
    if (MODE == 0) {
        const int L = blockIdx.y * 64 + blockIdx.x;
        const int g = L & 7, s = L >> 3;          // s < 192
        bx = g * 8 + (s & 7);                     // 0..63
        by = s >> 3;                              // 0..23
    } else {
        const int L = blockIdx.y * 32 + blockIdx.x;
        const int g = L & 7, s = L >> 3;          // s < 64
        bx = g * 4 + (s & 3);                     // 0..31
        by = s >> 2;                              // 0..15
    }
    const int i0   = bx * BM;
    const int j0   = by * BN;

    const unsigned short* ga[RA];
    const unsigned short* gb[RB];
    #pragma unroll
    for (int r = 0; r < RA; ++r) {
        const int slot = r * 256 + tid;
        const int row  = slot >> 3;
        const int gc   = (slot & 7) ^ swz(row);
        ga[r] = A + (size_t)(i0 + row) * EE + gc * 8;
    }
    #pragma unroll
    for (int r = 0; r < RB; ++r) {
        const int slot = r * 256 + tid;
        const int row  = slot >> 3;
        const int gc   = (slot & 7) ^ swz(row);
        gb[r] = Bw + (size_t)(j0 + row) * EE + gc * 8;
    }

    // Frag read offsets (ushort units), ks = K-substep of 32
    int ofsA[2][MT], ofsB[2][NT];
    #pragma unroll
    for (int mt = 0; mt < MT; ++mt) {
        const int row = wm * (BM / 2) + mt * 16 + l15;
        #pragma unroll
        for (int ks = 0; ks < 2; ++ks)
            ofsA[ks][mt] = row * 64 + (((ks * 4 + quad) ^ swz(row)) << 3);
    }
    #pragma unroll
    for (int nt = 0; nt < NT; ++nt) {
        const int col = wn * (BN / 2) + nt * 16 + l15;
        #pragma unroll
        for (int ks = 0; ks < 2; ++ks)
            ofsB[ks][nt] = col * 64 + (((ks * 4 + quad) ^ swz(col)) << 3);
    }

    floatx4 acc[MT][NT];
    #pragma unroll
    for (int mt = 0; mt < MT; ++mt)
        #pragma unroll
        for (int nt = 0; nt < NT; ++nt)
            acc[mt][nt] = (floatx4){0.f, 0.f, 0.f, 0.f};

    // Prologue: stage K-tile 0 into buffer 0.
    {
        unsigned short* nA = (unsigned short*)(smem);
        unsigned short* nB = (unsigned short*)(smem + ABYTES);
        #pragma unroll
        for (int r = 0; r < RA; ++r)
            gload16(ga[r], nA + (r * 256 + w * 64) * 8);
        #pragma unroll
        for (int r = 0; r < RB; ++r)
            gload16(gb[r], nB + (r * 256 + w * 64) * 8);
    }

    int cur = 0;
    for (int kk = 0; kk < EE; kk += 64) {
        // tile-k loads (issued last iter / prologue) done:
        asm volatile("s_waitcnt vmcnt(0)" ::: "memory");
        __builtin_amdgcn_s_barrier();

        // issue stage of tile k+1 into the other buffer IMMEDIATELY, so its
        // latency hides under this whole iteration's ds_reads + MFMAs.
        if (kk + 64 < EE) {
            unsigned short* nA = (unsigned short*)(smem + (cur ^ 1) * BUFB);
            unsigned short* nB = (unsigned short*)(smem + (cur ^ 1) * BUFB + ABYTES);
            #pragma unroll
            for (int r = 0; r < RA; ++r)
                gload16(ga[r] + kk + 64, nA + (r * 256 + w * 64) * 8);
            #pragma unroll
            for (int r = 0; r < RB; ++r)
                gload16(gb[r] + kk + 64, nB + (r * 256 + w * 64) * 8);
        }
        __builtin_amdgcn_sched_barrier(0);

        const unsigned short* lA = (const unsigned short*)(smem + cur * BUFB);
        const unsigned short* lB = (const unsigned short*)(smem + cur * BUFB + ABYTES);

        bf16x8 af[2][MT], bfr[2][NT];
        #pragma unroll
        for (int ks = 0; ks < 2; ++ks) {
            #pragma unroll
            for (int mt = 0; mt < MT; ++mt)
                af[ks][mt] = __builtin_bit_cast(bf16x8, *(const uint4*)&lA[ofsA[ks][mt]]);
            #pragma unroll
            for (int nt = 0; nt < NT; ++nt)
                bfr[ks][nt] = __builtin_bit_cast(bf16x8, *(const uint4*)&lB[ofsB[ks][nt]]);
        }

        #pragma unroll
        for (int ks = 0; ks < 2; ++ks)
            #pragma unroll
            for (int mt = 0; mt < MT; ++mt)
                #pragma unroll
                for (int nt = 0; nt < NT; ++nt)
                    acc[mt][nt] = __builtin_amdgcn_mfma_f32_16x16x32_bf16(
                        af[ks][mt], bfr[ks][nt], acc[mt][nt], 0, 0, 0);

        cur ^= 1;
    }

    if (MODE == 1) {
        float* dst = (float*)out0;
        #pragma unroll
        for (int nt = 0; nt < NT; ++nt) {
            const int j = j0 + wn * (BN / 2) + nt * 16 + l15;
            const float bb = b0[j];
            #pragma unroll
            for (int mt = 0; mt < MT; ++mt) {
                const int i = i0 + wm * (BM / 2) + mt * 16 + quad * 4;
                #pragma unroll
                for (int r2 = 0; r2 < 4; ++r2)
                    dst[(size_t)(i + r2) * EE + j] = acc[mt][nt][r2] + bb;
            }
        }
    } else {
        const int which = j0 >> 10;                 // 0=Q 1=K 2=V (block-uniform)
        const float scale = (which == 0) ? SCALE_Q : 1.0f;
        const float* bias = (which == 0) ? b0 : (which == 1) ? b1 : b2;
        if (which < 2) {
            unsigned short* dst = (unsigned short*)(which == 0 ? out0 : out1);
            #pragma unroll
            for (int nt = 0; nt < NT; ++nt) {
                const int j = (j0 & 1023) + wn * 64 + nt * 16 + l15;
                const int h = j >> 6, d = j & 63;
                const float bb = bias[j];
                #pragma unroll
                for (int mt = 0; mt < MT; ++mt) {
                    const int i = i0 + wm * (BM / 2) + mt * 16 + quad * 4;
                    #pragma unroll
                    for (int r2 = 0; r2 < 4; ++r2) {
                        const int ii = i + r2;
                        const int t = ii >> 1, b = ii & 1;
                        dst[((size_t)(b * HH + h) * TT + t) * DD + d] =
                            f2b((acc[mt][nt][r2] + bb) * scale);
                    }
                }
            }
        } else {
            // V: transpose through LDS to [B,H,D,T].
            // Wave tile = (BM/2) rows x 64 cols; tr[jl*68 + il], il < BM/2.
            __syncthreads();
            unsigned short* tr = (unsigned short*)smem + (size_t)w * 64 * 68;
            #pragma unroll
            for (int nt = 0; nt < NT; ++nt) {
                const int jl = nt * 16 + l15;
                const float bb = bias[(j0 & 1023) + wn * 64 + jl];
                #pragma unroll
                for (int mt = 0; mt < MT; ++mt) {
                    const int il0 = mt * 16 + quad * 4;
                    ushort4 h4;
                    h4.x = f2b(acc[mt][nt][0] + bb);
                    h4.y = f2b(acc[mt][nt][1] + bb);
                    h4.z = f2b(acc[mt][nt][2] + bb);
                    h4.w = f2b(acc[mt][nt][3] + bb);
                    *(ushort4*)&tr[jl * 68 + il0] = h4;
                }
            }
            __syncthreads();
            const int jg = (j0 & 1023) + wn * 64 + lane;
            const int h = jg >> 6, d = jg & 63;
            const int tb = (i0 + wm * (BM / 2)) >> 1;
            const unsigned short* rp = tr + (size_t)lane * 68;
            unsigned short* dstV = (unsigned short*)out2;
            #pragma unroll
            for (int g2 = 0; g2 < MT; ++g2) {     // (BM/2)/16 t-groups of 8
                union { unsigned short u[8]; uint4 v; } pe, po;
                #pragma unroll
                for (int k = 0; k < 8; ++k) {
                    pe.u[k] = rp[(g2 * 8 + k) * 2];
                    po.u[k] = rp[(g2 * 8 + k) * 2 + 1];
                }
                *(uint4*)&dstV[((size_t)(0 * HH + h) * DD + d) * TT + tb + g2 * 8] = pe.v;
                *(uint4*)&dstV[((size_t)(1 * HH + h) * DD + d) * TT + tb + g2 * 8] = po.v;
            }
        }
    }
}

// ---------------------------------------------------------------------------
// Flash attention v14 (R16 proven best, byte-identical): head-XCD swizzle +
// row-sum via MFMA (ones-vector trick, normalizer in output-row layout) +
// 4-slot ping-pong ring at 128-key rounds, one vmcnt(0)+s_barrier per round,
// setprio around compute. LDS 64KB, grid 512 = 2/CU. 43.9us measured.
// ---------------------------------------------------------------------------
__global__ __launch_bounds__(256)
void attn_mfma(const unsigned short* __restrict__ Q,
               const unsigned short* __restrict__ K,
               const unsigned short* __restrict__ Vt,
               unsigned short* __restrict__ cb)
{
    // ring[s][0] = K-sub [64 keys][64 d], ring[s][1] = V-sub [64 d][64 s]
    __shared__ __align__(16) unsigned short ring[4][2][64 * 64];   // 64 KB

    const int tid  = threadIdx.x;
    const int w    = tid >> 6;
    const int lane = tid & 63;
    const int quad = lane >> 4;
    const int l15  = lane & 15;
    // T1 head-XCD swizzle: XCD = blockIdx.x % 8 -> give each XCD 4 heads.
    const int bh   = (blockIdx.x & 7) * 4 + (blockIdx.x >> 3);
    const int tt   = blockIdx.y;

    const unsigned short* Qh = Q  + (size_t)bh * TT * DD;
    const unsigned short* Kh = K  + (size_t)bh * TT * DD;
    const unsigned short* Vh = Vt + (size_t)bh * DD * TT;

    const int q0w  = tt * 128 + w * 32;

    // Q B-frags: B[n=q (l15)][k=d (quad*8+j)], 2 q-subtiles x 2 d-steps
    bf16x8 qf[2][2];
    #pragma unroll
    for (int qn = 0; qn < 2; ++qn)
        #pragma unroll
        for (int kd = 0; kd < 2; ++kd)
            qf[qn][kd] = __builtin_bit_cast(bf16x8,
                *(const uint4*)&Qh[(size_t)(q0w + qn * 16 + l15) * DD + kd * 32 + quad * 8]);

    // ones B-frag for row-sum MFMA: B[k][n] = 1.0bf16 for all k,n
    const uint4 onesu = {0x3F803F80u, 0x3F803F80u, 0x3F803F80u, 0x3F803F80u};
    const bf16x8 ones = __builtin_bit_cast(bf16x8, onesu);

    // K staging addresses: kg[2p], kg[2p+1] cover the 64 keys of sub-parity p.
    const unsigned short* kg[4];
    #pragma unroll
    for (int r = 0; r < 4; ++r) {
        const int slot = r * 256 + tid;
        const int row  = slot >> 3;                  // 0..127 (key within 128-round)
        const int gc   = (slot & 7) ^ swz(row);
        kg[r] = Kh + (size_t)row * DD + gc * 8;      // + round*128*DD
    }
    // V staging addresses: vg[2p], vg[2p+1] cover s-subtile p ([64 d][64 s]).
    const unsigned short* vg[4];
    #pragma unroll
    for (int r = 0; r < 4; ++r) {
        const int s512 = (r & 1) * 256 + tid;
        const int rowd = s512 >> 3;                  // 0..63 (d)
        const int gc   = (s512 & 7) ^ swz(rowd);
        vg[r] = Vh + (size_t)rowd * TT + (r >> 1) * 64 + gc * 8;  // + round*128
    }

    // Frag read offsets within a 64x64 subtile (ushort units)
    int ofsKA[4][2], ofsVB[4][2];
    #pragma unroll
    for (int mt = 0; mt < 4; ++mt) {
        const int row = ((mt >> 1) << 5) + ((l15 >> 2) << 3) + ((mt & 1) << 2) + (l15 & 3);
        #pragma unroll
        for (int kd = 0; kd < 2; ++kd)
            ofsKA[mt][kd] = row * 64 + (((kd * 4 + quad) ^ swz(row)) << 3);
    }
    #pragma unroll
    for (int dn = 0; dn < 4; ++dn) {
        const int row = dn * 16 + l15;
        #pragma unroll
        for (int ks = 0; ks < 2; ++ks)
            ofsVB[dn][ks] = row * 64 + (((ks * 4 + quad) ^ swz(row)) << 3);
    }

    floatx4 cacc[4][2];
    #pragma unroll
    for (int dn = 0; dn < 4; ++dn)
        #pragma unroll
        for (int qn = 0; qn < 2; ++qn)
            cacc[dn][qn] = (floatx4){0.f, 0.f, 0.f, 0.f};
    floatx4 racc[2];
    racc[0] = (floatx4){0.f, 0.f, 0.f, 0.f};
    racc[1] = (floatx4){0.f, 0.f, 0.f, 0.f};

    // stage the 64-key sub-tile of parity p (compile-time literal at every
    // call site -> kg/vg indexed by constants, no scratch) at key-offset ko
    // into ring[slot] (runtime slot = LDS address arithmetic only).
    auto stage = [&](int p, size_t ko, int slot) {
        unsigned short* kd_ = &ring[slot][0][0];
        unsigned short* vd_ = &ring[slot][1][0];
        gload16(kg[2 * p]     + ko * DD, kd_ + (size_t)(0 * 256 + w * 64) * 8);
        gload16(kg[2 * p + 1] + ko * DD, kd_ + (size_t)(1 * 256 + w * 64) * 8);
        gload16(vg[2 * p]     + ko,      vd_ + (size_t)(0 * 256 + w * 64) * 8);
        gload16(vg[2 * p + 1] + ko,      vd_ + (size_t)(1 * 256 + w * 64) * 8);
    };

    // one 64-key compute step from ring[slot]
    auto compute_step = [&](int slot) {
        const unsigned short* ksub = &ring[slot][0][0];
        const unsigned short* vsub = &ring[slot][1][0];

        // QK^T (permuted keys) -> exp2 -> pack bf16 in registers
        uint2 pk[4][2];
        #pragma unroll
        for (int mt = 0; mt < 4; ++mt) {
            const bf16x8 ka0 = __builtin_bit_cast(bf16x8, *(const uint4*)&ksub[ofsKA[mt][0]]);
            const bf16x8 ka1 = __builtin_bit_cast(bf16x8, *(const uint4*)&ksub[ofsKA[mt][1]]);
            #pragma unroll
            for (int qn = 0; qn < 2; ++qn) {
                floatx4 s = (floatx4){0.f, 0.f, 0.f, 0.f};
                s = __builtin_amdgcn_mfma_f32_16x16x32_bf16(ka0, qf[qn][0], s, 0, 0, 0);
                s = __builtin_amdgcn_mfma_f32_16x16x32_bf16(ka1, qf[qn][1], s, 0, 0, 0);
                const float p0 = exp2_fast(s[0]);
                const float p1 = exp2_fast(s[1]);
                const float p2 = exp2_fast(s[2]);
                const float p3 = exp2_fast(s[3]);
                union { __hip_bfloat162 h2[2]; uint2 u; } c;
                c.h2[0] = __float22bfloat162_rn(make_float2(p0, p1));
                c.h2[1] = __float22bfloat162_rn(make_float2(p2, p3));
                pk[mt][qn] = c.u;
            }
        }
        // P A-frags from registers: A[m=q(l15)][k=quad*8 + mt*4 + reg]
        bf16x8 pa[2][2];
        #pragma unroll
        for (int qn = 0; qn < 2; ++qn) {
            union { uint2 d[2]; uint4 v; } a0, a1;
            a0.d[0] = pk[0][qn]; a0.d[1] = pk[1][qn];
            a1.d[0] = pk[2][qn]; a1.d[1] = pk[3][qn];
            pa[qn][0] = __builtin_bit_cast(bf16x8, a0.v);
            pa[qn][1] = __builtin_bit_cast(bf16x8, a1.v);
        }
        // row-sum via MFMA: racc[qn][j] (col-invariant) = sum_k P[q=quad*4+j][k]
        #pragma unroll
        for (int qn = 0; qn < 2; ++qn) {
            racc[qn] = __builtin_amdgcn_mfma_f32_16x16x32_bf16(pa[qn][0], ones, racc[qn], 0, 0, 0);
            racc[qn] = __builtin_amdgcn_mfma_f32_16x16x32_bf16(pa[qn][1], ones, racc[qn], 0, 0, 0);
        }
        // ctx += P . V^T
        #pragma unroll
        for (int dn = 0; dn < 4; ++dn) {
            const bf16x8 vb0 = __builtin_bit_cast(bf16x8, *(const uint4*)&vsub[ofsVB[dn][0]]);
            const bf16x8 vb1 = __builtin_bit_cast(bf16x8, *(const uint4*)&vsub[ofsVB[dn][1]]);
            #pragma unroll
            for (int qn = 0; qn < 2; ++qn) {
                cacc[dn][qn] = __builtin_amdgcn_mfma_f32_16x16x32_bf16(pa[qn][0], vb0, cacc[dn][qn], 0, 0, 0);
                cacc[dn][qn] = __builtin_amdgcn_mfma_f32_16x16x32_bf16(pa[qn][1], vb1, cacc[dn][qn], 0, 0, 0);
            }
        }
    };

    // Prologue: stage round 0 (keys 0..127) into slots 0,1.
    stage(0, 0, 0);
    stage(1, 0, 1);

    // 16 rounds x 128 keys. Round m computes slots {pb, pb+1}; stages the
    // next round's pair into the opposite slots {2-pb, 3-pb} (read at round
    // m-1, safe to overwrite after this round's barrier).
    #pragma unroll 1
    for (int m = 0; m < 16; ++m) {
        const int pb  = (m & 1) * 2;        // compute pair base
        const int npb = 2 - pb;             // stage pair base (opposite)
        const size_t ko = (size_t)(m + 1) * 128;

        asm volatile("s_waitcnt vmcnt(0)" ::: "memory");
        __builtin_amdgcn_s_barrier();
        if (m < 15) {
            stage(0, ko, npb);
            stage(1, ko, npb + 1);
        }
        __builtin_amdgcn_sched_barrier(0);
        __builtin_amdgcn_s_setprio(1);
        compute_step(pb);
        compute_step(pb + 1);
        __builtin_amdgcn_s_setprio(0);
    }

    // Epilogue: racc[qn][j] already holds the full-key row-sum for output
    // row q = quad*4 + j (col-invariant) — normalize directly, no shuffles.
    const int b = bh / HH, hh = bh % HH;
    #pragma unroll
    for (int qn = 0; qn < 2; ++qn) {
        float invq[4];
        #pragma unroll
        for (int j = 0; j < 4; ++j)
            invq[j] = 1.0f / racc[qn][j];
        #pragma unroll
        for (int dn = 0; dn < 4; ++dn) {
            const int e = hh * 64 + dn * 16 + l15;
            #pragma unroll
            for (int j = 0; j < 4; ++j) {
                const int t = q0w + qn * 16 + quad * 4 + j;
                cb[(size_t)(t * BB + b) * EE + e] = f2b(cacc[dn][qn][j] * invq[j]);
            }
        }
    }
}

// ---------------------------------------------------------------------------
// Workspace (ushort units, M1 = 1<<20):
// [0,4M)   pack X | [4M,7M) Wqkv
// [8M,12M) Q | [12M,16M) K | [16M,20M) Vt | [20M,24M) cb (final ctx, bf16)
// [24M,25M) Wo bf16   -> 50 MB total
// ---------------------------------------------------------------------------
extern "C" void kernel_launch(void* const* d_in, const int* in_sizes, int n_in,
                              void* d_out, int out_size, void* d_ws, size_t ws_size,
                              hipStream_t stream)
{
    const float* x  = (const float*)d_in[0];
    const float* Wq = (const float*)d_in[1];
    const float* bq = (const float*)d_in[2];
    const float* Wk = (const float*)d_in[3];
    const float* bk = (const float*)d_in[4];
    const float* Wv = (const float*)d_in[5];
    const float* bv = (const float*)d_in[6];
    const float* Wo = (const float*)d_in[7];
    const float* bo = (const float*)d_in[8];
    float* out = (float*)d_out;

    const size_t M1 = (size_t)1 << 20;
    unsigned short* base  = (unsigned short*)d_ws;
    unsigned short* xb    = base;             // 4M
    unsigned short* wqkv  = base + 4 * M1;    // 3M
    unsigned short* qb    = base + 8 * M1;    // 4M
    unsigned short* kb    = base + 12 * M1;   // 4M
    unsigned short* vtb   = base + 16 * M1;   // 4M
    unsigned short* cb    = base + 20 * M1;   // 4M
    unsigned short* wob   = base + 24 * M1;   // 1M

    dim3 blk(256);

    pack_bf16<<<dim3(4096), blk, 0, stream>>>(x, Wq, Wk, Wv, Wo, base, wob);

    gemm_mfma<0><<<dim3(RR / 64, 3072 / 128), blk, 0, stream>>>(
        xb, wqkv, bq, bk, bv, qb, kb, vtb);

    attn_mfma<<<dim3(BB * HH, TT / 128), blk, 0, stream>>>(qb, kb, vtb, cb);

    gemm_mfma<1><<<dim3(RR / 128, EE / 64), blk, 0, stream>>>(
        cb, wob, bo, nullptr, nullptr, out, nullptr, nullptr);
}

// Round 19
// 171.697 us; speedup vs baseline: 1.0113x; 1.0113x over previous
//
#include <hip/hip_runtime.h>
#include <hip/hip_bf16.h>
#include <math.h>

// Problem constants
#define TT 2048
#define BB 2
#define EE 1024
#define HH 16
#define DD 64
#define RR (TT*BB)   // 4096 rows (t*B+b)

typedef __bf16 bf16x8 __attribute__((ext_vector_type(8)));
typedef float  floatx4 __attribute__((ext_vector_type(4)));

// RNE float->bf16 bit conversion
__device__ __forceinline__ unsigned short f2b(float f) {
    union { float f; unsigned u; } x{f};
    return (unsigned short)((x.u + 0x7FFFu + ((x.u >> 16) & 1u)) >> 16);
}
__device__ __forceinline__ float b2f_lo(unsigned u) {
    union { unsigned u; float f; } x{u << 16}; return x.f;
}
__device__ __forceinline__ float b2f_hi(unsigned u) {
    union { unsigned u; float f; } x{u & 0xffff0000u}; return x.f;
}

// native v_exp_f32: computes 2^x
__device__ __forceinline__ float exp2_fast(float x) {
    return __builtin_amdgcn_exp2f(x);
}

typedef const __attribute__((address_space(1))) unsigned int as1_u32;
typedef __attribute__((address_space(3))) unsigned int as3_u32;
__device__ __forceinline__ void gload16(const void* g, void* l) {
    // async global->LDS, 16B per lane; LDS dest = wave-uniform base + lane*16
    __builtin_amdgcn_global_load_lds((as1_u32*)g, (as3_u32*)l, 16, 0, 0);
}

// Q projection scale: D^-0.5 * log2(e)  (so attention uses exp2 directly)
#define SCALE_Q 0.18033688011112042f

// LDS chunk swizzle over 8 chunks/row (measured 0 conflicts in round-8 attn
// for both the permuted-row and 16-consecutive-row b128 read patterns).
__device__ __forceinline__ int swz(int r) {
    return (r & 7) ^ (((r >> 3) & 3) << 1);
}

// ---------------------------------------------------------------------------
// pack: fp32 -> bf16. base (ushort): [0,4M) X | [4M,7M) Wq|Wk|Wv ; Wo -> wob.
// ---------------------------------------------------------------------------
__global__ __launch_bounds__(256)
void pack_bf16(const float* __restrict__ x,  const float* __restrict__ wq,
               const float* __restrict__ wk, const float* __restrict__ wv,
               const float* __restrict__ wo, unsigned short* __restrict__ base,
               unsigned short* __restrict__ wob)
{
    const size_t M4 = (size_t)4 << 20, M7 = (size_t)7 << 20;
    const size_t e0 = ((size_t)blockIdx.x * 256 + threadIdx.x) * 8;
    const float* src;
    unsigned short* dst;
    if (e0 < M4) {
        src = x + e0; dst = base + e0;
    } else if (e0 < M7) {
        const int seg = (int)((e0 >> 20) - 4);
        const float* wsrc[3] = {wq, wk, wv};
        src = wsrc[seg] + (e0 & ((1u << 20) - 1));
        dst = base + e0;
    } else {
        src = wo + (e0 - M7); dst = wob + (e0 - M7);
    }
    const float4 a = *(const float4*)src;
    const float4 b = *(const float4*)(src + 4);
    union { unsigned short u[8]; uint4 v; } p;
    p.u[0] = f2b(a.x); p.u[1] = f2b(a.y); p.u[2] = f2b(a.z); p.u[3] = f2b(a.w);
    p.u[4] = f2b(b.x); p.u[5] = f2b(b.y); p.u[6] = f2b(b.z); p.u[7] = f2b(b.w);
    *(uint4*)dst = p.v;
}

// ---------------------------------------------------------------------------
// bf16 MFMA GEMM, BK=64, 2-buffer pipeline with RAW barrier + counted wait.
// T1 XCD swizzle: L = by*32+bx; g=L&7, s=L>>3; bx'=g*4+(s&3), by'=s>>2.
// MODE 0 (QKV): 128x128 tile, grid (32,24)=768. LDS 64KB (2 blk/CU).
// MODE 1 (out): 128x64 tile, grid (32,16)=512. LDS 48KB (2/CU exactly).
// Session-established law for this 2-phase loop: >=32 MFMA/wave/barrier AND
// >=2 blocks/CU (R12/R14/R18 all confirm); 128x128 @ 2/CU is the optimum.
// ---------------------------------------------------------------------------
template<int MODE>
__global__ __launch_bounds__(256)
void gemm_mfma(const unsigned short* __restrict__ A,
               const unsigned short* __restrict__ Bw,
               const float* __restrict__ b0, const float* __restrict__ b1,
               const float* __restrict__ b2,
               void* __restrict__ out0, void* __restrict__ out1,
               void* __restrict__ out2)
{
    constexpr int BM = 128;
    constexpr int BN = (MODE == 0) ? 128 : 64;
    constexpr int MT = 4;                 // wave rows: 64
    constexpr int NT = (MODE == 0) ? 4 : 2;  // wave cols: 64 / 32
    constexpr int RA = BM / 32;           // staging rounds (256 slots each)
    constexpr int RB = BN / 32;
    constexpr int ABYTES = BM * 128;          // A K-tile bytes (BM x 64 bf16)
    constexpr int BUFB   = (BM + BN) * 128;   // one K-tile buffer (A then B)
    __shared__ __align__(16) unsigned char smem[2 * BUFB];

    const int tid  = threadIdx.x;
    const int w    = tid >> 6;
    const int lane = tid & 63;
    const int quad = lane >> 4;
    const int l15  = lane & 15;
    const int wm   = w & 1;
    const int wn   = w >> 1;

    // T1 XCD swizzle: linear dispatch id -> (XCD-stripe i0, j0)
    const int L = blockIdx.y * 32 + blockIdx.x;
    const int g = L & 7, s = L >> 3;
    const int bx = g * 4 + (s & 3);
    const int by = s >> 2;
    const int i0   = bx * BM;
    const int j0   = by * BN;

    const unsigned short* ga[RA];
    const unsigned short* gb[RB];
    #pragma unroll
    for (int r = 0; r < RA; ++r) {
        const int slot = r * 256 + tid;
        const int row  = slot >> 3;
        const int gc   = (slot & 7) ^ swz(row);
        ga[r] = A + (size_t)(i0 + row) * EE + gc * 8;
    }
    #pragma unroll
    for (int r = 0; r < RB; ++r) {
        const int slot = r * 256 + tid;
        const int row  = slot >> 3;
        const int gc   = (slot & 7) ^ swz(row);
        gb[r] = Bw + (size_t)(j0 + row) * EE + gc * 8;
    }

    // Frag read offsets (ushort units), ks = K-substep of 32
    int ofsA[2][MT], ofsB[2][NT];
    #pragma unroll
    for (int mt = 0; mt < MT; ++mt) {
        const int row = wm * 64 + mt * 16 + l15;
        #pragma unroll
        for (int ks = 0; ks < 2; ++ks)
            ofsA[ks][mt] = row * 64 + (((ks * 4 + quad) ^ swz(row)) << 3);
    }
    #pragma unroll
    for (int nt = 0; nt < NT; ++nt) {
        const int col = wn * (BN / 2) + nt * 16 + l15;
        #pragma unroll
        for (int ks = 0; ks < 2; ++ks)
            ofsB[ks][nt] = col * 64 + (((ks * 4 + quad) ^ swz(col)) << 3);
    }

    floatx4 acc[MT][NT];
    #pragma unroll
    for (int mt = 0; mt < MT; ++mt)
        #pragma unroll
        for (int nt = 0; nt < NT; ++nt)
            acc[mt][nt] = (floatx4){0.f, 0.f, 0.f, 0.f};

    // Prologue: stage K-tile 0 into buffer 0.
    {
        unsigned short* nA = (unsigned short*)(smem);
        unsigned short* nB = (unsigned short*)(smem + ABYTES);
        #pragma unroll
        for (int r = 0; r < RA; ++r)
            gload16(ga[r], nA + (r * 256 + w * 64) * 8);
        #pragma unroll
        for (int r = 0; r < RB; ++r)
            gload16(gb[r], nB + (r * 256 + w * 64) * 8);
    }

    int cur = 0;
    for (int kk = 0; kk < EE; kk += 64) {
        // tile-k loads (issued last iter / prologue) done:
        asm volatile("s_waitcnt vmcnt(0)" ::: "memory");
        __builtin_amdgcn_s_barrier();

        // issue stage of tile k+1 into the other buffer IMMEDIATELY, so its
        // latency hides under this whole iteration's ds_reads + MFMAs.
        if (kk + 64 < EE) {
            unsigned short* nA = (unsigned short*)(smem + (cur ^ 1) * BUFB);
            unsigned short* nB = (unsigned short*)(smem + (cur ^ 1) * BUFB + ABYTES);
            #pragma unroll
            for (int r = 0; r < RA; ++r)
                gload16(ga[r] + kk + 64, nA + (r * 256 + w * 64) * 8);
            #pragma unroll
            for (int r = 0; r < RB; ++r)
                gload16(gb[r] + kk + 64, nB + (r * 256 + w * 64) * 8);
        }
        __builtin_amdgcn_sched_barrier(0);

        const unsigned short* lA = (const unsigned short*)(smem + cur * BUFB);
        const unsigned short* lB = (const unsigned short*)(smem + cur * BUFB + ABYTES);

        bf16x8 af[2][MT], bfr[2][NT];
        #pragma unroll
        for (int ks = 0; ks < 2; ++ks) {
            #pragma unroll
            for (int mt = 0; mt < MT; ++mt)
                af[ks][mt] = __builtin_bit_cast(bf16x8, *(const uint4*)&lA[ofsA[ks][mt]]);
            #pragma unroll
            for (int nt = 0; nt < NT; ++nt)
                bfr[ks][nt] = __builtin_bit_cast(bf16x8, *(const uint4*)&lB[ofsB[ks][nt]]);
        }

        #pragma unroll
        for (int ks = 0; ks < 2; ++ks)
            #pragma unroll
            for (int mt = 0; mt < MT; ++mt)
                #pragma unroll
                for (int nt = 0; nt < NT; ++nt)
                    acc[mt][nt] = __builtin_amdgcn_mfma_f32_16x16x32_bf16(
                        af[ks][mt], bfr[ks][nt], acc[mt][nt], 0, 0, 0);

        cur ^= 1;
    }

    if (MODE == 1) {
        float* dst = (float*)out0;
        #pragma unroll
        for (int nt = 0; nt < NT; ++nt) {
            const int j = j0 + wn * 32 + nt * 16 + l15;
            const float bb = b0[j];
            #pragma unroll
            for (int mt = 0; mt < MT; ++mt) {
                const int i = i0 + wm * 64 + mt * 16 + quad * 4;
                #pragma unroll
                for (int r2 = 0; r2 < 4; ++r2)
                    dst[(size_t)(i + r2) * EE + j] = acc[mt][nt][r2] + bb;
            }
        }
    } else {
        const int which = j0 >> 10;                 // 0=Q 1=K 2=V (block-uniform)
        const float scale = (which == 0) ? SCALE_Q : 1.0f;
        const float* bias = (which == 0) ? b0 : (which == 1) ? b1 : b2;
        if (which < 2) {
            unsigned short* dst = (unsigned short*)(which == 0 ? out0 : out1);
            #pragma unroll
            for (int nt = 0; nt < NT; ++nt) {
                const int j = (j0 & 1023) + wn * 64 + nt * 16 + l15;
                const int h = j >> 6, d = j & 63;
                const float bb = bias[j];
                #pragma unroll
                for (int mt = 0; mt < MT; ++mt) {
                    const int i = i0 + wm * 64 + mt * 16 + quad * 4;
                    #pragma unroll
                    for (int r2 = 0; r2 < 4; ++r2) {
                        const int ii = i + r2;
                        const int t = ii >> 1, b = ii & 1;
                        dst[((size_t)(b * HH + h) * TT + t) * DD + d] =
                            f2b((acc[mt][nt][r2] + bb) * scale);
                    }
                }
            }
        } else {
            // V: transpose through LDS to [B,H,D,T]
            __syncthreads();
            unsigned short* tr = (unsigned short*)smem + (size_t)w * 64 * 68;
            #pragma unroll
            for (int nt = 0; nt < NT; ++nt) {
                const int jl = nt * 16 + l15;
                const float bb = bias[(j0 & 1023) + wn * 64 + jl];
                #pragma unroll
                for (int mt = 0; mt < MT; ++mt) {
                    const int il0 = mt * 16 + quad * 4;
                    ushort4 h4;
                    h4.x = f2b(acc[mt][nt][0] + bb);
                    h4.y = f2b(acc[mt][nt][1] + bb);
                    h4.z = f2b(acc[mt][nt][2] + bb);
                    h4.w = f2b(acc[mt][nt][3] + bb);
                    *(ushort4*)&tr[jl * 68 + il0] = h4;
                }
            }
            __syncthreads();
            const int jg = (j0 & 1023) + wn * 64 + lane;
            const int h = jg >> 6, d = jg & 63;
            const int tb = (i0 + wm * 64) >> 1;
            const unsigned short* rp = tr + (size_t)lane * 68;
            unsigned short* dstV = (unsigned short*)out2;
            #pragma unroll
            for (int g2 = 0; g2 < 4; ++g2) {
                union { unsigned short u[8]; uint4 v; } pe, po;
                #pragma unroll
                for (int k = 0; k < 8; ++k) {
                    pe.u[k] = rp[(g2 * 8 + k) * 2];
                    po.u[k] = rp[(g2 * 8 + k) * 2 + 1];
                }
                *(uint4*)&dstV[((size_t)(0 * HH + h) * DD + d) * TT + tb + g2 * 8] = pe.v;
                *(uint4*)&dstV[((size_t)(1 * HH + h) * DD + d) * TT + tb + g2 * 8] = po.v;
            }
        }
    }
}

// ---------------------------------------------------------------------------
// Flash attention v14 (session best, 43.9us measured): head-XCD swizzle +
// row-sum via MFMA (ones-vector trick, normalizer in output-row layout) +
// 4-slot ping-pong ring at 128-key rounds, one vmcnt(0)+s_barrier per round,
// setprio around compute. LDS 64KB, grid 512 = 2/CU.
// ---------------------------------------------------------------------------
__global__ __launch_bounds__(256)
void attn_mfma(const unsigned short* __restrict__ Q,
               const unsigned short* __restrict__ K,
               const unsigned short* __restrict__ Vt,
               unsigned short* __restrict__ cb)
{
    // ring[s][0] = K-sub [64 keys][64 d], ring[s][1] = V-sub [64 d][64 s]
    __shared__ __align__(16) unsigned short ring[4][2][64 * 64];   // 64 KB

    const int tid  = threadIdx.x;
    const int w    = tid >> 6;
    const int lane = tid & 63;
    const int quad = lane >> 4;
    const int l15  = lane & 15;
    // T1 head-XCD swizzle: XCD = blockIdx.x % 8 -> give each XCD 4 heads.
    const int bh   = (blockIdx.x & 7) * 4 + (blockIdx.x >> 3);
    const int tt   = blockIdx.y;

    const unsigned short* Qh = Q  + (size_t)bh * TT * DD;
    const unsigned short* Kh = K  + (size_t)bh * TT * DD;
    const unsigned short* Vh = Vt + (size_t)bh * DD * TT;

    const int q0w  = tt * 128 + w * 32;

    // Q B-frags: B[n=q (l15)][k=d (quad*8+j)], 2 q-subtiles x 2 d-steps
    bf16x8 qf[2][2];
    #pragma unroll
    for (int qn = 0; qn < 2; ++qn)
        #pragma unroll
        for (int kd = 0; kd < 2; ++kd)
            qf[qn][kd] = __builtin_bit_cast(bf16x8,
                *(const uint4*)&Qh[(size_t)(q0w + qn * 16 + l15) * DD + kd * 32 + quad * 8]);

    // ones B-frag for row-sum MFMA: B[k][n] = 1.0bf16 for all k,n
    const uint4 onesu = {0x3F803F80u, 0x3F803F80u, 0x3F803F80u, 0x3F803F80u};
    const bf16x8 ones = __builtin_bit_cast(bf16x8, onesu);

    // K staging addresses: kg[2p], kg[2p+1] cover the 64 keys of sub-parity p.
    const unsigned short* kg[4];
    #pragma unroll
    for (int r = 0; r < 4; ++r) {
        const int slot = r * 256 + tid;
        const int row  = slot >> 3;                  // 0..127 (key within 128-round)
        const int gc   = (slot & 7) ^ swz(row);
        kg[r] = Kh + (size_t)row * DD + gc * 8;      // + round*128*DD
    }
    // V staging addresses: vg[2p], vg[2p+1] cover s-subtile p ([64 d][64 s]).
    const unsigned short* vg[4];
    #pragma unroll
    for (int r = 0; r < 4; ++r) {
        const int s512 = (r & 1) * 256 + tid;
        const int rowd = s512 >> 3;                  // 0..63 (d)
        const int gc   = (s512 & 7) ^ swz(rowd);
        vg[r] = Vh + (size_t)rowd * TT + (r >> 1) * 64 + gc * 8;  // + round*128
    }

    // Frag read offsets within a 64x64 subtile (ushort units)
    int ofsKA[4][2], ofsVB[4][2];
    #pragma unroll
    for (int mt = 0; mt < 4; ++mt) {
        const int row = ((mt >> 1) << 5) + ((l15 >> 2) << 3) + ((mt & 1) << 2) + (l15 & 3);
        #pragma unroll
        for (int kd = 0; kd < 2; ++kd)
            ofsKA[mt][kd] = row * 64 + (((kd * 4 + quad) ^ swz(row)) << 3);
    }
    #pragma unroll
    for (int dn = 0; dn < 4; ++dn) {
        const int row = dn * 16 + l15;
        #pragma unroll
        for (int ks = 0; ks < 2; ++ks)
            ofsVB[dn][ks] = row * 64 + (((ks * 4 + quad) ^ swz(row)) << 3);
    }

    floatx4 cacc[4][2];
    #pragma unroll
    for (int dn = 0; dn < 4; ++dn)
        #pragma unroll
        for (int qn = 0; qn < 2; ++qn)
            cacc[dn][qn] = (floatx4){0.f, 0.f, 0.f, 0.f};
    floatx4 racc[2];
    racc[0] = (floatx4){0.f, 0.f, 0.f, 0.f};
    racc[1] = (floatx4){0.f, 0.f, 0.f, 0.f};

    // stage the 64-key sub-tile of parity p (compile-time literal at every
    // call site -> kg/vg indexed by constants, no scratch) at key-offset ko
    // into ring[slot] (runtime slot = LDS address arithmetic only).
    auto stage = [&](int p, size_t ko, int slot) {
        unsigned short* kd_ = &ring[slot][0][0];
        unsigned short* vd_ = &ring[slot][1][0];
        gload16(kg[2 * p]     + ko * DD, kd_ + (size_t)(0 * 256 + w * 64) * 8);
        gload16(kg[2 * p + 1] + ko * DD, kd_ + (size_t)(1 * 256 + w * 64) * 8);
        gload16(vg[2 * p]     + ko,      vd_ + (size_t)(0 * 256 + w * 64) * 8);
        gload16(vg[2 * p + 1] + ko,      vd_ + (size_t)(1 * 256 + w * 64) * 8);
    };

    // one 64-key compute step from ring[slot]
    auto compute_step = [&](int slot) {
        const unsigned short* ksub = &ring[slot][0][0];
        const unsigned short* vsub = &ring[slot][1][0];

        // QK^T (permuted keys) -> exp2 -> pack bf16 in registers
        uint2 pk[4][2];
        #pragma unroll
        for (int mt = 0; mt < 4; ++mt) {
            const bf16x8 ka0 = __builtin_bit_cast(bf16x8, *(const uint4*)&ksub[ofsKA[mt][0]]);
            const bf16x8 ka1 = __builtin_bit_cast(bf16x8, *(const uint4*)&ksub[ofsKA[mt][1]]);
            #pragma unroll
            for (int qn = 0; qn < 2; ++qn) {
                floatx4 s = (floatx4){0.f, 0.f, 0.f, 0.f};
                s = __builtin_amdgcn_mfma_f32_16x16x32_bf16(ka0, qf[qn][0], s, 0, 0, 0);
                s = __builtin_amdgcn_mfma_f32_16x16x32_bf16(ka1, qf[qn][1], s, 0, 0, 0);
                const float p0 = exp2_fast(s[0]);
                const float p1 = exp2_fast(s[1]);
                const float p2 = exp2_fast(s[2]);
                const float p3 = exp2_fast(s[3]);
                union { __hip_bfloat162 h2[2]; uint2 u; } c;
                c.h2[0] = __float22bfloat162_rn(make_float2(p0, p1));
                c.h2[1] = __float22bfloat162_rn(make_float2(p2, p3));
                pk[mt][qn] = c.u;
            }
        }
        // P A-frags from registers: A[m=q(l15)][k=quad*8 + mt*4 + reg]
        bf16x8 pa[2][2];
        #pragma unroll
        for (int qn = 0; qn < 2; ++qn) {
            union { uint2 d[2]; uint4 v; } a0, a1;
            a0.d[0] = pk[0][qn]; a0.d[1] = pk[1][qn];
            a1.d[0] = pk[2][qn]; a1.d[1] = pk[3][qn];
            pa[qn][0] = __builtin_bit_cast(bf16x8, a0.v);
            pa[qn][1] = __builtin_bit_cast(bf16x8, a1.v);
        }
        // row-sum via MFMA: racc[qn][j] (col-invariant) = sum_k P[q=quad*4+j][k]
        #pragma unroll
        for (int qn = 0; qn < 2; ++qn) {
            racc[qn] = __builtin_amdgcn_mfma_f32_16x16x32_bf16(pa[qn][0], ones, racc[qn], 0, 0, 0);
            racc[qn] = __builtin_amdgcn_mfma_f32_16x16x32_bf16(pa[qn][1], ones, racc[qn], 0, 0, 0);
        }
        // ctx += P . V^T
        #pragma unroll
        for (int dn = 0; dn < 4; ++dn) {
            const bf16x8 vb0 = __builtin_bit_cast(bf16x8, *(const uint4*)&vsub[ofsVB[dn][0]]);
            const bf16x8 vb1 = __builtin_bit_cast(bf16x8, *(const uint4*)&vsub[ofsVB[dn][1]]);
            #pragma unroll
            for (int qn = 0; qn < 2; ++qn) {
                cacc[dn][qn] = __builtin_amdgcn_mfma_f32_16x16x32_bf16(pa[qn][0], vb0, cacc[dn][qn], 0, 0, 0);
                cacc[dn][qn] = __builtin_amdgcn_mfma_f32_16x16x32_bf16(pa[qn][1], vb1, cacc[dn][qn], 0, 0, 0);
            }
        }
    };

    // Prologue: stage round 0 (keys 0..127) into slots 0,1.
    stage(0, 0, 0);
    stage(1, 0, 1);

    // 16 rounds x 128 keys. Round m computes slots {pb, pb+1}; stages the
    // next round's pair into the opposite slots {2-pb, 3-pb} (read at round
    // m-1, safe to overwrite after this round's barrier).
    #pragma unroll 1
    for (int m = 0; m < 16; ++m) {
        const int pb  = (m & 1) * 2;        // compute pair base
        const int npb = 2 - pb;             // stage pair base (opposite)
        const size_t ko = (size_t)(m + 1) * 128;

        asm volatile("s_waitcnt vmcnt(0)" ::: "memory");
        __builtin_amdgcn_s_barrier();
        if (m < 15) {
            stage(0, ko, npb);
            stage(1, ko, npb + 1);
        }
        __builtin_amdgcn_sched_barrier(0);
        __builtin_amdgcn_s_setprio(1);
        compute_step(pb);
        compute_step(pb + 1);
        __builtin_amdgcn_s_setprio(0);
    }

    // Epilogue: racc[qn][j] already holds the full-key row-sum for output
    // row q = quad*4 + j (col-invariant) — normalize directly, no shuffles.
    const int b = bh / HH, hh = bh % HH;
    #pragma unroll
    for (int qn = 0; qn < 2; ++qn) {
        float invq[4];
        #pragma unroll
        for (int j = 0; j < 4; ++j)
            invq[j] = 1.0f / racc[qn][j];
        #pragma unroll
        for (int dn = 0; dn < 4; ++dn) {
            const int e = hh * 64 + dn * 16 + l15;
            #pragma unroll
            for (int j = 0; j < 4; ++j) {
                const int t = q0w + qn * 16 + quad * 4 + j;
                cb[(size_t)(t * BB + b) * EE + e] = f2b(cacc[dn][qn][j] * invq[j]);
            }
        }
    }
}

// ---------------------------------------------------------------------------
// Workspace (ushort units, M1 = 1<<20):
// [0,4M)   pack X | [4M,7M) Wqkv
// [8M,12M) Q | [12M,16M) K | [16M,20M) Vt | [20M,24M) cb (final ctx, bf16)
// [24M,25M) Wo bf16   -> 50 MB total
// ---------------------------------------------------------------------------
extern "C" void kernel_launch(void* const* d_in, const int* in_sizes, int n_in,
                              void* d_out, int out_size, void* d_ws, size_t ws_size,
                              hipStream_t stream)
{
    const float* x  = (const float*)d_in[0];
    const float* Wq = (const float*)d_in[1];
    const float* bq = (const float*)d_in[2];
    const float* Wk = (const float*)d_in[3];
    const float* bk = (const float*)d_in[4];
    const float* Wv = (const float*)d_in[5];
    const float* bv = (const float*)d_in[6];
    const float* Wo = (const float*)d_in[7];
    const float* bo = (const float*)d_in[8];
    float* out = (float*)d_out;

    const size_t M1 = (size_t)1 << 20;
    unsigned short* base  = (unsigned short*)d_ws;
    unsigned short* xb    = base;             // 4M
    unsigned short* wqkv  = base + 4 * M1;    // 3M
    unsigned short* qb    = base + 8 * M1;    // 4M
    unsigned short* kb    = base + 12 * M1;   // 4M
    unsigned short* vtb   = base + 16 * M1;   // 4M
    unsigned short* cb    = base + 20 * M1;   // 4M
    unsigned short* wob   = base + 24 * M1;   // 1M

    dim3 blk(256);

    pack_bf16<<<dim3(4096), blk, 0, stream>>>(x, Wq, Wk, Wv, Wo, base, wob);

    gemm_mfma<0><<<dim3(RR / 128, 3072 / 128), blk, 0, stream>>>(
        xb, wqkv, bq, bk, bv, qb, kb, vtb);

    attn_mfma<<<dim3(BB * HH, TT / 128), blk, 0, stream>>>(qb, kb, vtb, cb);

    gemm_mfma<1><<<dim3(RR / 128, EE / 64), blk, 0, stream>>>(
        cb, wob, bo, nullptr, nullptr, out, nullptr, nullptr);
}